// Round 22
// baseline (100.945 us; speedup 1.0000x reference)
//
#include <hip/hip_runtime.h>
#include <hip/hip_bf16.h>

typedef __bf16 bf16_t;
typedef __bf16 bf16x8 __attribute__((ext_vector_type(8)));
typedef float f32x4 __attribute__((ext_vector_type(4)));

typedef __attribute__((address_space(3))) void lds_void;
typedef __attribute__((address_space(1))) void gbl_void;

static constexpr int NB  = 4096;  // batch
static constexpr int KIN = 768;   // D_IN
static constexpr int DD  = 256;   // D
static constexpr int FS  = NB * 32;   // F2 k-slice stride (elements)

// ---------------------------------------------------------------------------
// Kernel 1: pack W (KIN x DD, f32) -> Wt2 (bf16, k-slice-major). (R18 form)
// ---------------------------------------------------------------------------
__global__ __launch_bounds__(256) void pack_wt_kernel(
    const float* __restrict__ Wi, const float* __restrict__ Wx,
    bf16_t* __restrict__ Oi, bf16_t* __restrict__ Ox)
{
  __shared__ bf16_t tile[64][66];
  const int b = blockIdx.x;
  const bool isTxt = (b >= 48);
  const int t = isTxt ? b - 48 : b;
  const float* W = isTxt ? Wx : Wi;
  bf16_t* O      = isTxt ? Ox : Oi;
  const int k0 = (t % 12) * 64;     // KIN/64 = 12
  const int c0 = (t / 12) * 64;     // DD/64  = 4
  const int cl = threadIdx.x & 63;
  const int rw = threadIdx.x >> 6;

#pragma unroll
  for (int p = 0; p < 16; ++p) {
    const int kl = p * 4 + rw;
    tile[kl][cl] = (bf16_t)W[(size_t)(k0 + kl) * DD + c0 + cl];
  }
  __syncthreads();
#pragma unroll
  for (int p = 0; p < 16; ++p) {
    const int clo = p * 4 + rw;       // col-within-tile
    const int col = c0 + clo;
    const int k   = k0 + cl;
    O[(size_t)(k >> 5) * 8192 + col * 32 + (k & 31)] = tile[cl][clo];
  }
}

// ---------------------------------------------------------------------------
// Kernel 2: projection GEMM  F = X @ W + b — byte-identical to R19.
// ---------------------------------------------------------------------------
__global__ __launch_bounds__(256) void proj_kernel(
    const float* __restrict__ images, const float* __restrict__ texts,
    const bf16_t* __restrict__ Wti, const bf16_t* __restrict__ Wtt,
    const float* __restrict__ b_img, const float* __restrict__ b_txt,
    const float* __restrict__ cs_w,
    bf16_t* __restrict__ Fi, bf16_t* __restrict__ Ft,
    float* __restrict__ rni, float* __restrict__ si,
    float* __restrict__ rnt, float* __restrict__ st)
{
  __shared__ float xs[16 * KIN];    // 48 KB staged X tile (swizzled 16B units)
  __shared__ float lnsq[4][16];
  __shared__ float lsdt[4][16];

  const int bid = blockIdx.x;
  const bool isTxt = (bid >= 256);
  const float* X    = isTxt ? texts : images;
  const bf16_t* Wt  = isTxt ? Wtt : Wti;
  const float* bias = isTxt ? b_txt : b_img;
  const float* csw  = cs_w + (isTxt ? DD : 0);
  bf16_t* F     = isTxt ? Ft : Fi;
  float* rnorm  = isTxt ? rnt : rni;
  float* svec   = isTxt ? st : si;

  const int tid  = threadIdx.x;
  const int lane = tid & 63;
  const int wave = tid >> 6;
  const int lrow = lane & 15;
  const int g    = lane >> 4;
  const int rb   = (bid & 255) * 16;
  const int cwb  = wave * 64;

#pragma unroll
  for (int i = 0; i < 12; ++i) {
    const int U   = wave * 768 + i * 64 + lane;
    const int row = U / 192;
    const int su  = U - row * 192;
    const int ou  = su ^ (row & 7);
    const float* gp = X + (size_t)(rb + row) * KIN + ou * 4;
    char* lb = (char*)xs + wave * 12288 + i * 1024;   // wave-uniform base
    __builtin_amdgcn_global_load_lds((const gbl_void*)gp, (lds_void*)lb, 16, 0, 0);
  }
  __syncthreads();

  const f32x4 fzero = {0.f, 0.f, 0.f, 0.f};
  f32x4 acc[4];
#pragma unroll
  for (int n = 0; n < 4; ++n) acc[n] = fzero;

  const bf16_t* wtb  = Wt + (size_t)(cwb + lrow) * 32 + g * 8;
  const float*  xrow = xs + lrow * KIN;
  const int     rsw  = lrow & 7;

#pragma unroll 4
  for (int ks = 0; ks < KIN / 32; ++ks) {
    const int u0 = ks * 8 + g * 2;
    f32x4 x0 = *reinterpret_cast<const f32x4*>(xrow + ((u0    ) ^ rsw) * 4);
    f32x4 x1 = *reinterpret_cast<const f32x4*>(xrow + ((u0 + 1) ^ rsw) * 4);
    bf16x8 a;
#pragma unroll
    for (int e = 0; e < 4; ++e) { a[e] = (bf16_t)x0[e]; a[e + 4] = (bf16_t)x1[e]; }
#pragma unroll
    for (int n = 0; n < 4; ++n) {
      bf16x8 bfr = *reinterpret_cast<const bf16x8*>(wtb + ks * 8192 + n * 512);
      acc[n] = __builtin_amdgcn_mfma_f32_16x16x32_bf16(a, bfr, acc[n], 0, 0, 0);
    }
  }

  float nsq[4] = {0.f, 0.f, 0.f, 0.f};
  float sdt[4] = {0.f, 0.f, 0.f, 0.f};
#pragma unroll
  for (int n = 0; n < 4; ++n) {
    const int col = cwb + n * 16 + lrow;
    const float bn = bias[col];
    const float wn = csw[col];
    const size_t cbase = (size_t)(col >> 5) * FS + (col & 31);
#pragma unroll
    for (int r = 0; r < 4; ++r) {
      float v = acc[n][r] + bn;
      const int row = rb + g * 4 + r;
      F[cbase + row * 32] = (bf16_t)v;    // k-slice-major store
      nsq[r] += v * v;
      sdt[r] += v * wn;
    }
  }
#pragma unroll
  for (int msk = 8; msk >= 1; msk >>= 1) {
#pragma unroll
    for (int r = 0; r < 4; ++r) {
      nsq[r] += __shfl_xor(nsq[r], msk, 64);
      sdt[r] += __shfl_xor(sdt[r], msk, 64);
    }
  }
  if (lrow == 0) {
#pragma unroll
    for (int r = 0; r < 4; ++r) {
      lnsq[wave][g * 4 + r] = nsq[r];
      lsdt[wave][g * 4 + r] = sdt[r];
    }
  }
  __syncthreads();
  if (tid < 16) {
    float tn = 0.f, ts = 0.f;
#pragma unroll
    for (int w2 = 0; w2 < 4; ++w2) { tn += lnsq[w2][tid]; ts += lsdt[w2][tid]; }
    rnorm[rb + tid] = 1.0f / sqrtf(tn);
    svec [rb + tid] = ts;
  }
}

// ---------------------------------------------------------------------------
// Kernel 3: sim = Fi @ Ft^T + fused epilogue.
// R21 change (sim only): tile reshaped 128x128 -> 32x512 so each output
// buffer is written in 2 KB contiguous runs per row (was 512 B at 16 KB
// stride) -> ~4x better DRAM page locality in the streaming phase. Same
// 1024 blocks, 4 waves (wave tile 16x256, acc[16]), 64 KB XOR-swizzled LDS
// bounce, NT edge-tile register prefetch, plain interleaved f32x4 stores,
// k-slice-major coalesced K-loop.
// ---------------------------------------------------------------------------
__global__ __launch_bounds__(256, 2) void sim_kernel(
    const bf16_t* __restrict__ Fi, const bf16_t* __restrict__ Ft,
    const float* __restrict__ rni, const float* __restrict__ si,
    const float* __restrict__ rnt, const float* __restrict__ st,
    const float* __restrict__ cs_b, const float* __restrict__ edge,
    float* __restrict__ out_final, float* __restrict__ out_sim,
    float* __restrict__ out_causal)
{
  __shared__ float smem[32 * 512];   // 64 KB, XOR-swizzled

  // XCD swizzle: 1024 blocks, 8 XCDs -> 128 consecutive tiles per XCD.
  const int bid = blockIdx.x;
  const int swz = (bid & 7) * 128 + (bid >> 3);
  const int bx = swz & 7;    // col tile (4096/512 = 8)
  const int by = swz >> 3;   // row tile (4096/32 = 128)

  const int tid  = threadIdx.x;
  const int lane = tid & 63;
  const int wave = tid >> 6;
  const int wr = wave >> 1;      // 0..1 (16-row half)
  const int wc = wave & 1;       // 0..1 (256-col half)
  const int lrow = lane & 15;
  const int g    = lane >> 4;

  const int rowG0 = by * 32;
  const int colG0 = bx * 512;
  const int rowBase = rowG0 + wr * 16;
  const int colBase = colG0 + wc * 256;

  // ---- async-stage: issue the whole edge tile up front (16 NT f32x4) ----
  f32x4 ewr[16];
#pragma unroll
  for (int it = 0; it < 16; ++it) {
    const int e = (it * 256 + tid) * 4;
    const int r = e >> 9;        // 0..31
    const int c = e & 511;       // multiple of 4
    ewr[it] = __builtin_nontemporal_load(
        reinterpret_cast<const f32x4*>(edge + (size_t)(rowG0 + r) * NB + colG0 + c));
  }
  asm volatile("" ::: "memory");   // pin prefetch issue before the K-loop

  const f32x4 fzero = {0.f, 0.f, 0.f, 0.f};
  f32x4 acc[16];
#pragma unroll
  for (int n = 0; n < 16; ++n) acc[n] = fzero;

  // k-slice-major per-lane bases (contiguous 1 KB per wave load)
  const size_t arow = (size_t)(rowBase + lrow) * 32 + g * 8;
  const size_t brow = (size_t)(colBase + lrow) * 32 + g * 8;

  for (int ks = 0; ks < DD / 32; ++ks) {
    const size_t so = (size_t)ks * FS;
    const bf16x8 a = *reinterpret_cast<const bf16x8*>(Fi + so + arow);
    bf16x8 b[16];
#pragma unroll
    for (int n = 0; n < 16; ++n)
      b[n] = *reinterpret_cast<const bf16x8*>(Ft + so + brow + n * 512);
#pragma unroll
    for (int n = 0; n < 16; ++n)
      acc[n] = __builtin_amdgcn_mfma_f32_16x16x32_bf16(a, b[n], acc[n], 0, 0, 0);
  }

  float rntv[16];
#pragma unroll
  for (int n = 0; n < 16; ++n) rntv[n] = rnt[colBase + n * 16 + lrow];
  float rnv[4];
#pragma unroll
  for (int r = 0; r < 4; ++r) rnv[r] = rni[rowBase + g * 4 + r];

  // Fragment -> LDS (normalized sim). XOR swizzle: col ^= (row&7)<<2.
#pragma unroll
  for (int n = 0; n < 16; ++n) {
    const int cl = wc * 256 + n * 16 + lrow;
#pragma unroll
    for (int r = 0; r < 4; ++r) {
      const int rl = wr * 16 + g * 4 + r;          // tile-local row (0..31)
      smem[rl * 512 + (cl ^ ((rl & 7) << 2))] = acc[n][r] * rnv[r] * rntv[n];
    }
  }
  __syncthreads();

  // Streaming epilogue: 2 KB contiguous runs per row per buffer.
  const float cb = cs_b[0];
#pragma unroll
  for (int it = 0; it < 16; ++it) {
    const int e = (it * 256 + tid) * 4;
    const int r = e >> 9;        // 0..31
    const int c = e & 511;       // multiple of 4
    const f32x4 sv4 = *reinterpret_cast<const f32x4*>(&smem[r * 512 + (c ^ ((r & 7) << 2))]);
    const float sir = si[rowG0 + r];
    const f32x4 st4 = *reinterpret_cast<const f32x4*>(st + colG0 + c);
    const size_t idx = (size_t)(rowG0 + r) * NB + colG0 + c;
    f32x4 ca4, fin4;
#pragma unroll
    for (int j = 0; j < 4; ++j) {
      const float strength = sir + st4[j] + cb;
      ca4[j]  = ewr[it][j] * strength;
      fin4[j] = sv4[j] + 0.3f * ca4[j];
    }
    *reinterpret_cast<f32x4*>(out_sim    + idx) = sv4;
    *reinterpret_cast<f32x4*>(out_causal + idx) = ca4;
    *reinterpret_cast<f32x4*>(out_final  + idx) = fin4;
  }
}

// ---------------------------------------------------------------------------
extern "C" void kernel_launch(void* const* d_in, const int* in_sizes, int n_in,
                              void* d_out, int out_size, void* d_ws, size_t ws_size,
                              hipStream_t stream) {
  const float* images = (const float*)d_in[0];
  const float* texts  = (const float*)d_in[1];
  const float* W_img  = (const float*)d_in[2];
  const float* b_img  = (const float*)d_in[3];
  const float* W_txt  = (const float*)d_in[4];
  const float* b_txt  = (const float*)d_in[5];
  const float* cs_w   = (const float*)d_in[6];
  const float* cs_b   = (const float*)d_in[7];
  const float* edge   = (const float*)d_in[8];

  float* out_final  = (float*)d_out;
  float* out_sim    = out_final + (size_t)NB * NB;
  float* out_causal = out_sim   + (size_t)NB * NB;

  // Workspace layout (~4.9 MiB total)
  char* ws = (char*)d_ws;
  bf16_t* Fi  = (bf16_t*)ws;                     // 4096*256 bf16 (k-slice-major)
  bf16_t* Ft  = Fi  + (size_t)NB * DD;           // 4096*256 bf16 (k-slice-major)
  bf16_t* Wti = Ft  + (size_t)NB * DD;           // 256*768 bf16 (k-slice-major)
  bf16_t* Wtt = Wti + (size_t)DD * KIN;          // 256*768 bf16 (k-slice-major)
  float*  rni = (float*)(Wtt + (size_t)DD * KIN);
  float*  siv = rni + NB;
  float*  rnt = siv + NB;
  float*  stv = rnt + NB;

  pack_wt_kernel<<<96, 256, 0, stream>>>(W_img, W_txt, Wti, Wtt);
  proj_kernel<<<512, 256, 0, stream>>>(images, texts, Wti, Wtt, b_img, b_txt, cs_w,
                                       Fi, Ft, rni, siv, rnt, stv);
  sim_kernel<<<1024, 256, 0, stream>>>(Fi, Ft, rni, siv, rnt, stv, cs_b, edge,
                                       out_final, out_sim, out_causal);
}

// Round 23
// 89.269 us; speedup vs baseline: 1.1308x; 1.1308x over previous
//
#include <hip/hip_runtime.h>
#include <hip/hip_bf16.h>

typedef __bf16 bf16_t;
typedef __bf16 bf16x8 __attribute__((ext_vector_type(8)));
typedef float f32x4 __attribute__((ext_vector_type(4)));

typedef __attribute__((address_space(3))) void lds_void;
typedef __attribute__((address_space(1))) void gbl_void;

static constexpr int NB  = 4096;  // batch
static constexpr int KIN = 768;   // D_IN
static constexpr int DD  = 256;   // D
static constexpr int FS  = NB * 32;   // F2 k-slice stride (elements)

// ---------------------------------------------------------------------------
// Kernel 1: pack W (KIN x DD, f32) -> Wt2 (bf16, k-slice-major). (R18 form)
// ---------------------------------------------------------------------------
__global__ __launch_bounds__(256) void pack_wt_kernel(
    const float* __restrict__ Wi, const float* __restrict__ Wx,
    bf16_t* __restrict__ Oi, bf16_t* __restrict__ Ox)
{
  __shared__ bf16_t tile[64][66];
  const int b = blockIdx.x;
  const bool isTxt = (b >= 48);
  const int t = isTxt ? b - 48 : b;
  const float* W = isTxt ? Wx : Wi;
  bf16_t* O      = isTxt ? Ox : Oi;
  const int k0 = (t % 12) * 64;     // KIN/64 = 12
  const int c0 = (t / 12) * 64;     // DD/64  = 4
  const int cl = threadIdx.x & 63;
  const int rw = threadIdx.x >> 6;

#pragma unroll
  for (int p = 0; p < 16; ++p) {
    const int kl = p * 4 + rw;
    tile[kl][cl] = (bf16_t)W[(size_t)(k0 + kl) * DD + c0 + cl];
  }
  __syncthreads();
#pragma unroll
  for (int p = 0; p < 16; ++p) {
    const int clo = p * 4 + rw;       // col-within-tile
    const int col = c0 + clo;
    const int k   = k0 + cl;
    O[(size_t)(k >> 5) * 8192 + col * 32 + (k & 31)] = tile[cl][clo];
  }
}

// ---------------------------------------------------------------------------
// Kernel 2: projection GEMM  F = X @ W + b — byte-identical to R19.
// ---------------------------------------------------------------------------
__global__ __launch_bounds__(256) void proj_kernel(
    const float* __restrict__ images, const float* __restrict__ texts,
    const bf16_t* __restrict__ Wti, const bf16_t* __restrict__ Wtt,
    const float* __restrict__ b_img, const float* __restrict__ b_txt,
    const float* __restrict__ cs_w,
    bf16_t* __restrict__ Fi, bf16_t* __restrict__ Ft,
    float* __restrict__ rni, float* __restrict__ si,
    float* __restrict__ rnt, float* __restrict__ st)
{
  __shared__ float xs[16 * KIN];    // 48 KB staged X tile (swizzled 16B units)
  __shared__ float lnsq[4][16];
  __shared__ float lsdt[4][16];

  const int bid = blockIdx.x;
  const bool isTxt = (bid >= 256);
  const float* X    = isTxt ? texts : images;
  const bf16_t* Wt  = isTxt ? Wtt : Wti;
  const float* bias = isTxt ? b_txt : b_img;
  const float* csw  = cs_w + (isTxt ? DD : 0);
  bf16_t* F     = isTxt ? Ft : Fi;
  float* rnorm  = isTxt ? rnt : rni;
  float* svec   = isTxt ? st : si;

  const int tid  = threadIdx.x;
  const int lane = tid & 63;
  const int wave = tid >> 6;
  const int lrow = lane & 15;
  const int g    = lane >> 4;
  const int rb   = (bid & 255) * 16;
  const int cwb  = wave * 64;

#pragma unroll
  for (int i = 0; i < 12; ++i) {
    const int U   = wave * 768 + i * 64 + lane;
    const int row = U / 192;
    const int su  = U - row * 192;
    const int ou  = su ^ (row & 7);
    const float* gp = X + (size_t)(rb + row) * KIN + ou * 4;
    char* lb = (char*)xs + wave * 12288 + i * 1024;   // wave-uniform base
    __builtin_amdgcn_global_load_lds((const gbl_void*)gp, (lds_void*)lb, 16, 0, 0);
  }
  __syncthreads();

  const f32x4 fzero = {0.f, 0.f, 0.f, 0.f};
  f32x4 acc[4];
#pragma unroll
  for (int n = 0; n < 4; ++n) acc[n] = fzero;

  const bf16_t* wtb  = Wt + (size_t)(cwb + lrow) * 32 + g * 8;
  const float*  xrow = xs + lrow * KIN;
  const int     rsw  = lrow & 7;

#pragma unroll 4
  for (int ks = 0; ks < KIN / 32; ++ks) {
    const int u0 = ks * 8 + g * 2;
    f32x4 x0 = *reinterpret_cast<const f32x4*>(xrow + ((u0    ) ^ rsw) * 4);
    f32x4 x1 = *reinterpret_cast<const f32x4*>(xrow + ((u0 + 1) ^ rsw) * 4);
    bf16x8 a;
#pragma unroll
    for (int e = 0; e < 4; ++e) { a[e] = (bf16_t)x0[e]; a[e + 4] = (bf16_t)x1[e]; }
#pragma unroll
    for (int n = 0; n < 4; ++n) {
      bf16x8 bfr = *reinterpret_cast<const bf16x8*>(wtb + ks * 8192 + n * 512);
      acc[n] = __builtin_amdgcn_mfma_f32_16x16x32_bf16(a, bfr, acc[n], 0, 0, 0);
    }
  }

  float nsq[4] = {0.f, 0.f, 0.f, 0.f};
  float sdt[4] = {0.f, 0.f, 0.f, 0.f};
#pragma unroll
  for (int n = 0; n < 4; ++n) {
    const int col = cwb + n * 16 + lrow;
    const float bn = bias[col];
    const float wn = csw[col];
    const size_t cbase = (size_t)(col >> 5) * FS + (col & 31);
#pragma unroll
    for (int r = 0; r < 4; ++r) {
      float v = acc[n][r] + bn;
      const int row = rb + g * 4 + r;
      F[cbase + row * 32] = (bf16_t)v;    // k-slice-major store
      nsq[r] += v * v;
      sdt[r] += v * wn;
    }
  }
#pragma unroll
  for (int msk = 8; msk >= 1; msk >>= 1) {
#pragma unroll
    for (int r = 0; r < 4; ++r) {
      nsq[r] += __shfl_xor(nsq[r], msk, 64);
      sdt[r] += __shfl_xor(sdt[r], msk, 64);
    }
  }
  if (lrow == 0) {
#pragma unroll
    for (int r = 0; r < 4; ++r) {
      lnsq[wave][g * 4 + r] = nsq[r];
      lsdt[wave][g * 4 + r] = sdt[r];
    }
  }
  __syncthreads();
  if (tid < 16) {
    float tn = 0.f, ts = 0.f;
#pragma unroll
    for (int w2 = 0; w2 < 4; ++w2) { tn += lnsq[w2][tid]; ts += lsdt[w2][tid]; }
    rnorm[rb + tid] = 1.0f / sqrtf(tn);
    svec [rb + tid] = ts;
  }
}

// ---------------------------------------------------------------------------
// Kernel 3: sim = Fi @ Ft^T + fused epilogue — R19 form with ONE change:
// the edge-tile prefetch uses PLAIN (cached) loads instead of NT, so the
// 256 MB L3 can retain the 64 MB edge matrix across graph replays (R5's
// FETCH=44MB already showed partial L3 service; NT suppresses retention).
// Everything else byte-identical to R19.
// ---------------------------------------------------------------------------
__global__ __launch_bounds__(256, 2) void sim_kernel(
    const bf16_t* __restrict__ Fi, const bf16_t* __restrict__ Ft,
    const float* __restrict__ rni, const float* __restrict__ si,
    const float* __restrict__ rnt, const float* __restrict__ st,
    const float* __restrict__ cs_b, const float* __restrict__ edge,
    float* __restrict__ out_final, float* __restrict__ out_sim,
    float* __restrict__ out_causal)
{
  extern __shared__ float smem[];   // 128*128 f32 = 64 KB, XOR-swizzled

  const int bid = blockIdx.x;
  const int swz = (bid & 7) * 128 + (bid >> 3);
  const int bx = swz & 31;   // col tile
  const int by = swz >> 5;   // row tile

  const int tid  = threadIdx.x;
  const int lane = tid & 63;
  const int wave = tid >> 6;
  const int wr = wave >> 1;
  const int wc = wave & 1;
  const int lrow = lane & 15;
  const int g    = lane >> 4;

  const int rowG0 = by * 128;
  const int colG0 = bx * 128;
  const int rowBase = rowG0 + wr * 64;
  const int colBase = colG0 + wc * 64;

  // ---- stage the edge tile into registers up front (16 PLAIN f32x4) ----
  f32x4 ewr[16];
#pragma unroll
  for (int it = 0; it < 16; ++it) {
    const int e = (it * 256 + tid) * 4;
    const int r = e >> 7;        // 0..127
    const int c = e & 127;       // multiple of 4
    ewr[it] = *reinterpret_cast<const f32x4*>(
        edge + (size_t)(rowG0 + r) * NB + colG0 + c);
  }
  asm volatile("" ::: "memory");   // pin prefetch issue before the K-loop

  const f32x4 fzero = {0.f, 0.f, 0.f, 0.f};
  f32x4 acc[4][4];
#pragma unroll
  for (int m = 0; m < 4; ++m)
#pragma unroll
    for (int n = 0; n < 4; ++n) acc[m][n] = fzero;

  // k-slice-major per-lane bases (contiguous 1 KB per wave load)
  const size_t arow = (size_t)(rowBase + lrow) * 32 + g * 8;
  const size_t brow = (size_t)(colBase + lrow) * 32 + g * 8;

#pragma unroll 2
  for (int ks = 0; ks < DD / 32; ++ks) {
    const size_t so = (size_t)ks * FS;
    bf16x8 a[4], b[4];
#pragma unroll
    for (int m = 0; m < 4; ++m)
      a[m] = *reinterpret_cast<const bf16x8*>(Fi + so + arow + m * 512);
#pragma unroll
    for (int n = 0; n < 4; ++n)
      b[n] = *reinterpret_cast<const bf16x8*>(Ft + so + brow + n * 512);
#pragma unroll
    for (int m = 0; m < 4; ++m)
#pragma unroll
      for (int n = 0; n < 4; ++n)
        acc[m][n] = __builtin_amdgcn_mfma_f32_16x16x32_bf16(a[m], b[n], acc[m][n], 0, 0, 0);
  }

  float rntv[4];
#pragma unroll
  for (int n = 0; n < 4; ++n) rntv[n] = rnt[colBase + n * 16 + lrow];
  float rnv[4][4];
#pragma unroll
  for (int m = 0; m < 4; ++m)
#pragma unroll
    for (int r = 0; r < 4; ++r) rnv[m][r] = rni[rowBase + m * 16 + g * 4 + r];

  // Fragment -> LDS (normalized sim). XOR swizzle: col ^= (row&7)<<2.
#pragma unroll
  for (int m = 0; m < 4; ++m) {
#pragma unroll
    for (int n = 0; n < 4; ++n) {
#pragma unroll
      for (int r = 0; r < 4; ++r) {
        const int rl = wr * 64 + m * 16 + g * 4 + r;
        const int cl = wc * 64 + n * 16 + lrow;
        smem[rl * 128 + (cl ^ ((rl & 7) << 2))] = acc[m][n][r] * rnv[m][r] * rntv[n];
      }
    }
  }
  __syncthreads();

  // Streaming epilogue: pure store stream (edge already in registers).
  const float cb = cs_b[0];
#pragma unroll
  for (int it = 0; it < 16; ++it) {
    const int e = (it * 256 + tid) * 4;
    const int r = e >> 7;        // 0..127
    const int c = e & 127;       // multiple of 4
    const f32x4 sv4 = *reinterpret_cast<const f32x4*>(&smem[r * 128 + (c ^ ((r & 7) << 2))]);
    const float sir = si[rowG0 + r];
    const f32x4 st4 = *reinterpret_cast<const f32x4*>(st + colG0 + c);
    const size_t idx = (size_t)(rowG0 + r) * NB + colG0 + c;
    f32x4 ca4, fin4;
#pragma unroll
    for (int j = 0; j < 4; ++j) {
      const float strength = sir + st4[j] + cb;
      ca4[j]  = ewr[it][j] * strength;
      fin4[j] = sv4[j] + 0.3f * ca4[j];
    }
    *reinterpret_cast<f32x4*>(out_sim    + idx) = sv4;
    *reinterpret_cast<f32x4*>(out_causal + idx) = ca4;
    *reinterpret_cast<f32x4*>(out_final  + idx) = fin4;
  }
}

// ---------------------------------------------------------------------------
extern "C" void kernel_launch(void* const* d_in, const int* in_sizes, int n_in,
                              void* d_out, int out_size, void* d_ws, size_t ws_size,
                              hipStream_t stream) {
  const float* images = (const float*)d_in[0];
  const float* texts  = (const float*)d_in[1];
  const float* W_img  = (const float*)d_in[2];
  const float* b_img  = (const float*)d_in[3];
  const float* W_txt  = (const float*)d_in[4];
  const float* b_txt  = (const float*)d_in[5];
  const float* cs_w   = (const float*)d_in[6];
  const float* cs_b   = (const float*)d_in[7];
  const float* edge   = (const float*)d_in[8];

  float* out_final  = (float*)d_out;
  float* out_sim    = out_final + (size_t)NB * NB;
  float* out_causal = out_sim   + (size_t)NB * NB;

  // Workspace layout (~4.9 MiB total)
  char* ws = (char*)d_ws;
  bf16_t* Fi  = (bf16_t*)ws;                     // 4096*256 bf16 (k-slice-major)
  bf16_t* Ft  = Fi  + (size_t)NB * DD;           // 4096*256 bf16 (k-slice-major)
  bf16_t* Wti = Ft  + (size_t)NB * DD;           // 256*768 bf16 (k-slice-major)
  bf16_t* Wtt = Wti + (size_t)DD * KIN;          // 256*768 bf16 (k-slice-major)
  float*  rni = (float*)(Wtt + (size_t)DD * KIN);
  float*  siv = rni + NB;
  float*  rnt = siv + NB;
  float*  stv = rnt + NB;

  pack_wt_kernel<<<96, 256, 0, stream>>>(W_img, W_txt, Wti, Wtt);
  proj_kernel<<<512, 256, 0, stream>>>(images, texts, Wti, Wtt, b_img, b_txt, cs_w,
                                       Fi, Ft, rni, siv, rnt, stv);
  sim_kernel<<<1024, 256, 65536, stream>>>(Fi, Ft, rni, siv, rnt, stv, cs_b, edge,
                                           out_final, out_sim, out_causal);
}

// Round 24
// 81.258 us; speedup vs baseline: 1.2423x; 1.0986x over previous
//
#include <hip/hip_runtime.h>
#include <hip/hip_bf16.h>

typedef __bf16 bf16_t;
typedef __bf16 bf16x8 __attribute__((ext_vector_type(8)));
typedef float f32x4 __attribute__((ext_vector_type(4)));

typedef __attribute__((address_space(3))) void lds_void;
typedef __attribute__((address_space(1))) void gbl_void;

static constexpr int NB  = 4096;  // batch
static constexpr int KIN = 768;   // D_IN
static constexpr int DD  = 256;   // D
static constexpr int FS  = NB * 32;   // F2 k-slice stride (elements)

// ---------------------------------------------------------------------------
// R23 = exact R19 restore (best measured: 81.7 us).
// Kernel 1: pack W (KIN x DD, f32) -> Wt2 (bf16, k-slice-major).
// ---------------------------------------------------------------------------
__global__ __launch_bounds__(256) void pack_wt_kernel(
    const float* __restrict__ Wi, const float* __restrict__ Wx,
    bf16_t* __restrict__ Oi, bf16_t* __restrict__ Ox)
{
  __shared__ bf16_t tile[64][66];
  const int b = blockIdx.x;
  const bool isTxt = (b >= 48);
  const int t = isTxt ? b - 48 : b;
  const float* W = isTxt ? Wx : Wi;
  bf16_t* O      = isTxt ? Ox : Oi;
  const int k0 = (t % 12) * 64;     // KIN/64 = 12
  const int c0 = (t / 12) * 64;     // DD/64  = 4
  const int cl = threadIdx.x & 63;
  const int rw = threadIdx.x >> 6;

#pragma unroll
  for (int p = 0; p < 16; ++p) {
    const int kl = p * 4 + rw;
    tile[kl][cl] = (bf16_t)W[(size_t)(k0 + kl) * DD + c0 + cl];
  }
  __syncthreads();
#pragma unroll
  for (int p = 0; p < 16; ++p) {
    const int clo = p * 4 + rw;       // col-within-tile
    const int col = c0 + clo;
    const int k   = k0 + cl;
    O[(size_t)(k >> 5) * 8192 + col * 32 + (k & 31)] = tile[cl][clo];
  }
}

// ---------------------------------------------------------------------------
// Kernel 2: projection GEMM  F = X @ W + b  (4096 x 768 x 256), bf16 MFMA.
// Async global_load_lds X stage (swizzled source, linear LDS dest),
// XOR-swizzled ds_reads; k-slice-major Wt2 B-loads (1 KB contiguous/wave);
// k-slice-major F2 stores; 512 blocks x 4 waves; fused norm/strength reduce.
// ---------------------------------------------------------------------------
__global__ __launch_bounds__(256) void proj_kernel(
    const float* __restrict__ images, const float* __restrict__ texts,
    const bf16_t* __restrict__ Wti, const bf16_t* __restrict__ Wtt,
    const float* __restrict__ b_img, const float* __restrict__ b_txt,
    const float* __restrict__ cs_w,
    bf16_t* __restrict__ Fi, bf16_t* __restrict__ Ft,
    float* __restrict__ rni, float* __restrict__ si,
    float* __restrict__ rnt, float* __restrict__ st)
{
  __shared__ float xs[16 * KIN];    // 48 KB staged X tile (swizzled 16B units)
  __shared__ float lnsq[4][16];
  __shared__ float lsdt[4][16];

  const int bid = blockIdx.x;
  const bool isTxt = (bid >= 256);
  const float* X    = isTxt ? texts : images;
  const bf16_t* Wt  = isTxt ? Wtt : Wti;
  const float* bias = isTxt ? b_txt : b_img;
  const float* csw  = cs_w + (isTxt ? DD : 0);
  bf16_t* F     = isTxt ? Ft : Fi;
  float* rnorm  = isTxt ? rnt : rni;
  float* svec   = isTxt ? st : si;

  const int tid  = threadIdx.x;
  const int lane = tid & 63;
  const int wave = tid >> 6;
  const int lrow = lane & 15;
  const int g    = lane >> 4;
  const int rb   = (bid & 255) * 16;
  const int cwb  = wave * 64;

#pragma unroll
  for (int i = 0; i < 12; ++i) {
    const int U   = wave * 768 + i * 64 + lane;
    const int row = U / 192;
    const int su  = U - row * 192;
    const int ou  = su ^ (row & 7);
    const float* gp = X + (size_t)(rb + row) * KIN + ou * 4;
    char* lb = (char*)xs + wave * 12288 + i * 1024;   // wave-uniform base
    __builtin_amdgcn_global_load_lds((const gbl_void*)gp, (lds_void*)lb, 16, 0, 0);
  }
  __syncthreads();

  const f32x4 fzero = {0.f, 0.f, 0.f, 0.f};
  f32x4 acc[4];
#pragma unroll
  for (int n = 0; n < 4; ++n) acc[n] = fzero;

  const bf16_t* wtb  = Wt + (size_t)(cwb + lrow) * 32 + g * 8;
  const float*  xrow = xs + lrow * KIN;
  const int     rsw  = lrow & 7;

#pragma unroll 4
  for (int ks = 0; ks < KIN / 32; ++ks) {
    const int u0 = ks * 8 + g * 2;
    f32x4 x0 = *reinterpret_cast<const f32x4*>(xrow + ((u0    ) ^ rsw) * 4);
    f32x4 x1 = *reinterpret_cast<const f32x4*>(xrow + ((u0 + 1) ^ rsw) * 4);
    bf16x8 a;
#pragma unroll
    for (int e = 0; e < 4; ++e) { a[e] = (bf16_t)x0[e]; a[e + 4] = (bf16_t)x1[e]; }
#pragma unroll
    for (int n = 0; n < 4; ++n) {
      bf16x8 bfr = *reinterpret_cast<const bf16x8*>(wtb + ks * 8192 + n * 512);
      acc[n] = __builtin_amdgcn_mfma_f32_16x16x32_bf16(a, bfr, acc[n], 0, 0, 0);
    }
  }

  float nsq[4] = {0.f, 0.f, 0.f, 0.f};
  float sdt[4] = {0.f, 0.f, 0.f, 0.f};
#pragma unroll
  for (int n = 0; n < 4; ++n) {
    const int col = cwb + n * 16 + lrow;
    const float bn = bias[col];
    const float wn = csw[col];
    const size_t cbase = (size_t)(col >> 5) * FS + (col & 31);
#pragma unroll
    for (int r = 0; r < 4; ++r) {
      float v = acc[n][r] + bn;
      const int row = rb + g * 4 + r;
      F[cbase + row * 32] = (bf16_t)v;    // k-slice-major store
      nsq[r] += v * v;
      sdt[r] += v * wn;
    }
  }
#pragma unroll
  for (int msk = 8; msk >= 1; msk >>= 1) {
#pragma unroll
    for (int r = 0; r < 4; ++r) {
      nsq[r] += __shfl_xor(nsq[r], msk, 64);
      sdt[r] += __shfl_xor(sdt[r], msk, 64);
    }
  }
  if (lrow == 0) {
#pragma unroll
    for (int r = 0; r < 4; ++r) {
      lnsq[wave][g * 4 + r] = nsq[r];
      lsdt[wave][g * 4 + r] = sdt[r];
    }
  }
  __syncthreads();
  if (tid < 16) {
    float tn = 0.f, ts = 0.f;
#pragma unroll
    for (int w2 = 0; w2 < 4; ++w2) { tn += lnsq[w2][tid]; ts += lsdt[w2][tid]; }
    rnorm[rb + tid] = 1.0f / sqrtf(tn);
    svec [rb + tid] = ts;
  }
}

// ---------------------------------------------------------------------------
// Kernel 3: sim = Fi @ Ft^T + fused epilogue (R19 form).
// 128x128 tile, 1024 blocks, 4 waves x 4x4 fragments; k-slice-major
// coalesced fragment loads (1 KB contiguous/wave); NT edge-tile register
// prefetch before the K-loop; 64 KB XOR-swizzled LDS bounce; interleaved
// plain f32x4 stores.
// ---------------------------------------------------------------------------
__global__ __launch_bounds__(256, 2) void sim_kernel(
    const bf16_t* __restrict__ Fi, const bf16_t* __restrict__ Ft,
    const float* __restrict__ rni, const float* __restrict__ si,
    const float* __restrict__ rnt, const float* __restrict__ st,
    const float* __restrict__ cs_b, const float* __restrict__ edge,
    float* __restrict__ out_final, float* __restrict__ out_sim,
    float* __restrict__ out_causal)
{
  extern __shared__ float smem[];   // 128*128 f32 = 64 KB, XOR-swizzled

  const int bid = blockIdx.x;
  const int swz = (bid & 7) * 128 + (bid >> 3);
  const int bx = swz & 31;   // col tile
  const int by = swz >> 5;   // row tile

  const int tid  = threadIdx.x;
  const int lane = tid & 63;
  const int wave = tid >> 6;
  const int wr = wave >> 1;
  const int wc = wave & 1;
  const int lrow = lane & 15;
  const int g    = lane >> 4;

  const int rowG0 = by * 128;
  const int colG0 = bx * 128;
  const int rowBase = rowG0 + wr * 64;
  const int colBase = colG0 + wc * 64;

  // ---- async-stage: issue the whole edge tile up front (16 NT f32x4) ----
  f32x4 ewr[16];
#pragma unroll
  for (int it = 0; it < 16; ++it) {
    const int e = (it * 256 + tid) * 4;
    const int r = e >> 7;        // 0..127
    const int c = e & 127;       // multiple of 4
    ewr[it] = __builtin_nontemporal_load(
        reinterpret_cast<const f32x4*>(edge + (size_t)(rowG0 + r) * NB + colG0 + c));
  }
  asm volatile("" ::: "memory");   // pin prefetch issue before the K-loop

  const f32x4 fzero = {0.f, 0.f, 0.f, 0.f};
  f32x4 acc[4][4];
#pragma unroll
  for (int m = 0; m < 4; ++m)
#pragma unroll
    for (int n = 0; n < 4; ++n) acc[m][n] = fzero;

  // k-slice-major per-lane bases (contiguous 1 KB per wave load)
  const size_t arow = (size_t)(rowBase + lrow) * 32 + g * 8;
  const size_t brow = (size_t)(colBase + lrow) * 32 + g * 8;

#pragma unroll 2
  for (int ks = 0; ks < DD / 32; ++ks) {
    const size_t so = (size_t)ks * FS;
    bf16x8 a[4], b[4];
#pragma unroll
    for (int m = 0; m < 4; ++m)
      a[m] = *reinterpret_cast<const bf16x8*>(Fi + so + arow + m * 512);
#pragma unroll
    for (int n = 0; n < 4; ++n)
      b[n] = *reinterpret_cast<const bf16x8*>(Ft + so + brow + n * 512);
#pragma unroll
    for (int m = 0; m < 4; ++m)
#pragma unroll
      for (int n = 0; n < 4; ++n)
        acc[m][n] = __builtin_amdgcn_mfma_f32_16x16x32_bf16(a[m], b[n], acc[m][n], 0, 0, 0);
  }

  float rntv[4];
#pragma unroll
  for (int n = 0; n < 4; ++n) rntv[n] = rnt[colBase + n * 16 + lrow];
  float rnv[4][4];
#pragma unroll
  for (int m = 0; m < 4; ++m)
#pragma unroll
    for (int r = 0; r < 4; ++r) rnv[m][r] = rni[rowBase + m * 16 + g * 4 + r];

  // Fragment -> LDS (normalized sim). XOR swizzle: col ^= (row&7)<<2.
#pragma unroll
  for (int m = 0; m < 4; ++m) {
#pragma unroll
    for (int n = 0; n < 4; ++n) {
#pragma unroll
      for (int r = 0; r < 4; ++r) {
        const int rl = wr * 64 + m * 16 + g * 4 + r;
        const int cl = wc * 64 + n * 16 + lrow;
        smem[rl * 128 + (cl ^ ((rl & 7) << 2))] = acc[m][n][r] * rnv[m][r] * rntv[n];
      }
    }
  }
  __syncthreads();

  // Streaming epilogue: pure store stream (edge already in registers).
  const float cb = cs_b[0];
#pragma unroll
  for (int it = 0; it < 16; ++it) {
    const int e = (it * 256 + tid) * 4;
    const int r = e >> 7;        // 0..127
    const int c = e & 127;       // multiple of 4
    const f32x4 sv4 = *reinterpret_cast<const f32x4*>(&smem[r * 128 + (c ^ ((r & 7) << 2))]);
    const float sir = si[rowG0 + r];
    const f32x4 st4 = *reinterpret_cast<const f32x4*>(st + colG0 + c);
    const size_t idx = (size_t)(rowG0 + r) * NB + colG0 + c;
    f32x4 ca4, fin4;
#pragma unroll
    for (int j = 0; j < 4; ++j) {
      const float strength = sir + st4[j] + cb;
      ca4[j]  = ewr[it][j] * strength;
      fin4[j] = sv4[j] + 0.3f * ca4[j];
    }
    *reinterpret_cast<f32x4*>(out_sim    + idx) = sv4;
    *reinterpret_cast<f32x4*>(out_causal + idx) = ca4;
    *reinterpret_cast<f32x4*>(out_final  + idx) = fin4;
  }
}

// ---------------------------------------------------------------------------
extern "C" void kernel_launch(void* const* d_in, const int* in_sizes, int n_in,
                              void* d_out, int out_size, void* d_ws, size_t ws_size,
                              hipStream_t stream) {
  const float* images = (const float*)d_in[0];
  const float* texts  = (const float*)d_in[1];
  const float* W_img  = (const float*)d_in[2];
  const float* b_img  = (const float*)d_in[3];
  const float* W_txt  = (const float*)d_in[4];
  const float* b_txt  = (const float*)d_in[5];
  const float* cs_w   = (const float*)d_in[6];
  const float* cs_b   = (const float*)d_in[7];
  const float* edge   = (const float*)d_in[8];

  float* out_final  = (float*)d_out;
  float* out_sim    = out_final + (size_t)NB * NB;
  float* out_causal = out_sim   + (size_t)NB * NB;

  // Workspace layout (~4.9 MiB total)
  char* ws = (char*)d_ws;
  bf16_t* Fi  = (bf16_t*)ws;                     // 4096*256 bf16 (k-slice-major)
  bf16_t* Ft  = Fi  + (size_t)NB * DD;           // 4096*256 bf16 (k-slice-major)
  bf16_t* Wti = Ft  + (size_t)NB * DD;           // 256*768 bf16 (k-slice-major)
  bf16_t* Wtt = Wti + (size_t)DD * KIN;          // 256*768 bf16 (k-slice-major)
  float*  rni = (float*)(Wtt + (size_t)DD * KIN);
  float*  siv = rni + NB;
  float*  rnt = siv + NB;
  float*  stv = rnt + NB;

  pack_wt_kernel<<<96, 256, 0, stream>>>(W_img, W_txt, Wti, Wtt);
  proj_kernel<<<512, 256, 0, stream>>>(images, texts, Wti, Wtt, b_img, b_txt, cs_w,
                                       Fi, Ft, rni, siv, rnt, stv);
  sim_kernel<<<1024, 256, 65536, stream>>>(Fi, Ft, rni, siv, rnt, stv, cs_b, edge,
                                           out_final, out_sim, out_causal);
}